// Round 7
// baseline (365.357 us; speedup 1.0000x reference)
//
#include <hip/hip_runtime.h>
#include <hip/hip_bf16.h>

// B=4096, L=50, D=64, E=128, CAT=384, U=256, V=100000. fp32 I/O, int32 ids.
// Factored: h = relu(qvec + [K|K*q]·[W_k;W_qk]);  qvec = b_hide + q·W_q
// scores = (h·W_out + b_out)*mask ; out = scores·K
//
// R7: spill-free pipelining. R6 spilled kvf (32 regs) because its live range
// crossed the MFMA phase (acc: 64 regs) under a 170-reg cap -> 140 MB scratch
// writes. Fix: (a) launch_bounds(256,2) [cap 256]; (b) issue next-batch
// gathers AFTER part[] extraction (acc dead) so kvf never overlaps acc;
// (c) A2 LDS buffer removed - A2 fragments computed on the fly from Kb
// fragments x q (kills a store phase + barrier + 17 KB LDS); (d) batch-
// invariant W_q fragments hoisted to regs once per block; (e) grid 512 x
// NB=8: exactly 2 co-resident blocks/CU, no sequential slots.

#define L_SEQ 50
#define D_EMB 64
#define E_DIM 128
#define U_DIM 256
#define V_SZ  100000
#define KSTR  136   // LDS row stride (bf16): rows 16B-aligned
#define NB    8     // batches per block; grid = 4096/NB = 512

typedef __bf16 bf16x8 __attribute__((ext_vector_type(8)));
typedef float  f32x4  __attribute__((ext_vector_type(4)));

// packed weights: g_Wp[kk8*2048 + n*8 + j] = bf16(W_hide[kk8*8+j][n]), kk8<48
// kk8 0..15 -> W_q rows (qvec); 16..31 -> W_k rows; 32..47 -> W_qk rows
__device__ __bf16 g_Wp[48 * 256 * 8];

__global__ __launch_bounds__(256) void pack_kernel(const float* __restrict__ W) {
  int e = blockIdx.x * 256 + threadIdx.x;          // grid 384 -> exact cover
  int kk8 = e >> 11, rem = e & 2047, n = rem >> 3, j = rem & 7;
  g_Wp[e] = (__bf16)W[(kk8 * 8 + j) * 256 + n];
}

__global__ __launch_bounds__(256, 2) void din_main_kernel(
    const int* __restrict__ qid_item, const int* __restrict__ qid_cate,
    const int* __restrict__ seq_item, const int* __restrict__ seq_cate,
    const int* __restrict__ mask,
    const float* __restrict__ emb_item,
    const float* __restrict__ emb_cate,
    const float* __restrict__ b_hide,
    const float* __restrict__ W_out,
    const float* __restrict__ b_out,
    float* __restrict__ out) {
  __shared__ alignas(16) __bf16 Kb[64 * KSTR];     // bf16(K)   17408 B
  __shared__ alignas(16) float qrowf[2][E_DIM];    // fp32 q, double-buffered
  __shared__ float qv_s[U_DIM];
  __shared__ float scpart[4][64];
  __shared__ float scores[64];

  const int t = threadIdx.x;
  const int b0 = blockIdx.x * NB;
  const int r = t >> 2, q4 = t & 3;
  const int col0 = q4 * 32;
  const int wave = t >> 6, lane = t & 63;
  const int m = lane & 15, quad = lane >> 4;
  const float vsel = (r < L_SEQ) ? 1.f : 0.f;      // zero pad rows 50..63

  const float* embsel  = (q4 < 2) ? emb_item : emb_cate;
  const float* qembsel = (t < 16) ? emb_item : emb_cate;
  const int qcol = (t < 16) ? t * 4 : 64 + (t - 16) * 4;

  // ---- batch-invariant params in regs ----
  float wo_r[4];
#pragma unroll
  for (int nt = 0; nt < 4; ++nt) wo_r[nt] = W_out[wave * 64 + nt * 16 + m];
  const float bh_r = b_hide[t];
  const float bo_r = b_out[0];
  bf16x8 wq[16];                                   // W_q fragments (hoisted)
#pragma unroll
  for (int c8 = 0; c8 < 16; ++c8)
    wq[c8] = *(const bf16x8*)&g_Wp[(c8 << 11) + t * 8];

  // id/mask loaders (clamped batch index: harmless dup reads near the end)
#define LOAD_IDS(ii, sdst, qdst) {                                          \
    int bb_ = b0 + (ii);                                                    \
    int s_ = 0;                                                             \
    if (r < L_SEQ) {                                                        \
      s_ = (q4 < 2 ? seq_item : seq_cate)[bb_ * L_SEQ + r];                 \
      if ((unsigned)s_ >= (unsigned)V_SZ) s_ = 0;                           \
    }                                                                       \
    (sdst) = s_;                                                            \
    int q_ = 0;                                                             \
    if (t < 32) {                                                           \
      q_ = (t < 16 ? qid_item : qid_cate)[bb_];                             \
      if ((unsigned)q_ >= (unsigned)V_SZ) q_ = 0;                           \
    }                                                                       \
    (qdst) = q_; }

#define ISSUE_GATHER(sidv, qidv) {                                          \
    const float4* s4_ =                                                     \
        (const float4*)(embsel + (size_t)(sidv) * D_EMB + (q4 & 1) * 32);   \
    _Pragma("unroll")                                                       \
    for (int jj = 0; jj < 8; ++jj) kvf[jj] = s4_[jj];                       \
    if (t < 32)                                                             \
      qbuf = *(const float4*)(qembsel + (size_t)(qidv) * D_EMB + (t & 15) * 4); }

  // ---- prologue: pipeline prime (batch 0 gathers, batch 1 ids) ----
  float4 kvf[8], qbuf;
  int sid_g, qid_g;
  LOAD_IDS(0, sid_g, qid_g);
  float msk_cur =
      (t < L_SEQ && mask[b0 * L_SEQ + t] != 0) ? 1.f : 0.f;
  ISSUE_GATHER(sid_g, qid_g);
  LOAD_IDS((NB > 1 ? 1 : 0), sid_g, qid_g);
  if (t < 32) *(float4*)&qrowf[0][qcol] = qbuf;
  __syncthreads();   // qrowf[0] visible

  for (int i = 0; i < NB; ++i) {
    const int cur = i & 1;

    // ---- (a) store kvf -> Kb (bf16, pad rows zeroed) ----
#pragma unroll
    for (int h = 0; h < 2; ++h) {
      bf16x8 kb0, kb1;
#pragma unroll
      for (int jj = 0; jj < 2; ++jj) {
        float4 kf = kvf[h * 4 + jj];
        kb0[jj * 4 + 0] = (__bf16)(kf.x * vsel);
        kb0[jj * 4 + 1] = (__bf16)(kf.y * vsel);
        kb0[jj * 4 + 2] = (__bf16)(kf.z * vsel);
        kb0[jj * 4 + 3] = (__bf16)(kf.w * vsel);
      }
#pragma unroll
      for (int jj = 0; jj < 2; ++jj) {
        float4 kf = kvf[h * 4 + 2 + jj];
        kb1[jj * 4 + 0] = (__bf16)(kf.x * vsel);
        kb1[jj * 4 + 1] = (__bf16)(kf.y * vsel);
        kb1[jj * 4 + 2] = (__bf16)(kf.z * vsel);
        kb1[jj * 4 + 3] = (__bf16)(kf.w * vsel);
      }
      *(bf16x8*)&Kb[r * KSTR + col0 + h * 16]     = kb0;
      *(bf16x8*)&Kb[r * KSTR + col0 + h * 16 + 8] = kb1;
    }

    // ---- (b) qvec: qv_s[t] = b_hide[t] + q·W_q[:,t] (regs-only weights) ----
    {
      float accq = bh_r;
#pragma unroll
      for (int c8 = 0; c8 < 16; ++c8) {
        bf16x8 w8 = wq[c8];
        float4 qa = *(const float4*)&qrowf[cur][c8 * 8];
        float4 qb = *(const float4*)&qrowf[cur][c8 * 8 + 4];
        accq += qa.x * (float)w8[0] + qa.y * (float)w8[1] +
                qa.z * (float)w8[2] + qa.w * (float)w8[3] +
                qb.x * (float)w8[4] + qb.y * (float)w8[5] +
                qb.z * (float)w8[6] + qb.w * (float)w8[7];
      }
      qv_s[t] = accq;
    }
    __syncthreads();   // B1: Kb + qv_s visible

    // ---- (d) MFMA: 4 half-steps; A2 fragments on the fly from Kb x q ----
    f32x4 acc[4][4];
#pragma unroll
    for (int mt = 0; mt < 4; ++mt)
#pragma unroll
      for (int nt = 0; nt < 4; ++nt) acc[mt][nt] = (f32x4){0.f, 0.f, 0.f, 0.f};
#pragma unroll
    for (int s = 0; s < 4; ++s) {
      const int klocal = s * 32 + quad * 8;
      bf16x8 afr[4], bfrk[4], bfrq[4];
#pragma unroll
      for (int mt = 0; mt < 4; ++mt)
        afr[mt] = *(const bf16x8*)&Kb[(mt * 16 + m) * KSTR + klocal];
      const float4 qa = *(const float4*)&qrowf[cur][klocal];
      const float4 qb = *(const float4*)&qrowf[cur][klocal + 4];
#pragma unroll
      for (int nt = 0; nt < 4; ++nt) {
        const int noff = (wave * 64 + nt * 16 + m) * 8;
        bfrk[nt] = *(const bf16x8*)&g_Wp[((16 + s * 4 + quad) << 11) + noff];
        bfrq[nt] = *(const bf16x8*)&g_Wp[((32 + s * 4 + quad) << 11) + noff];
      }
#pragma unroll
      for (int mt = 0; mt < 4; ++mt)
#pragma unroll
        for (int nt = 0; nt < 4; ++nt)
          acc[mt][nt] = __builtin_amdgcn_mfma_f32_16x16x32_bf16(
              afr[mt], bfrk[nt], acc[mt][nt], 0, 0, 0);
#pragma unroll
      for (int mt = 0; mt < 4; ++mt) {
        bf16x8 a2;
        a2[0] = (__bf16)((float)afr[mt][0] * qa.x);
        a2[1] = (__bf16)((float)afr[mt][1] * qa.y);
        a2[2] = (__bf16)((float)afr[mt][2] * qa.z);
        a2[3] = (__bf16)((float)afr[mt][3] * qa.w);
        a2[4] = (__bf16)((float)afr[mt][4] * qb.x);
        a2[5] = (__bf16)((float)afr[mt][5] * qb.y);
        a2[6] = (__bf16)((float)afr[mt][6] * qb.z);
        a2[7] = (__bf16)((float)afr[mt][7] * qb.w);
#pragma unroll
        for (int nt = 0; nt < 4; ++nt)
          acc[mt][nt] = __builtin_amdgcn_mfma_f32_16x16x32_bf16(
              a2, bfrq[nt], acc[mt][nt], 0, 0, 0);
      }
    }

    // ---- (e) part[] from acc (acc dies here), THEN prefetch next batch ----
    float qv[4];
#pragma unroll
    for (int nt = 0; nt < 4; ++nt) qv[nt] = qv_s[wave * 64 + nt * 16 + m];
    float part[16];
#pragma unroll
    for (int mt = 0; mt < 4; ++mt)
#pragma unroll
      for (int rg = 0; rg < 4; ++rg) {
        float sum = 0.f;
#pragma unroll
        for (int nt = 0; nt < 4; ++nt) {
          float h = acc[mt][nt][rg] + qv[nt];
          h = fmaxf(h, 0.f);
          sum += h * wo_r[nt];
        }
        part[mt * 4 + rg] = sum;
      }
    if (i + 1 < NB) ISSUE_GATHER(sid_g, qid_g);      // kvf live only epilogue->(a)
    { int ii = (i + 2 < NB) ? i + 2 : NB - 1; LOAD_IDS(ii, sid_g, qid_g); }
    float msk_nx;
    { int bb = b0 + ((i + 1 < NB) ? i + 1 : NB - 1);
      msk_nx = (t < L_SEQ && mask[bb * L_SEQ + t] != 0) ? 1.f : 0.f; }

    // ---- (f) 16-lane reduce + cross-wave combine ----
#pragma unroll
    for (int off = 1; off < 16; off <<= 1)
#pragma unroll
      for (int k = 0; k < 16; ++k)
        part[k] += __shfl_xor(part[k], off, 64);
    if (m == 0) {
#pragma unroll
      for (int mt = 0; mt < 4; ++mt)
#pragma unroll
        for (int rg = 0; rg < 4; ++rg)
          scpart[wave][mt * 16 + quad * 4 + rg] = part[mt * 4 + rg];
    }
    __syncthreads();   // B2: scpart ready
    if (t < 64) {
      float sc = scpart[0][t] + scpart[1][t] + scpart[2][t] + scpart[3][t] + bo_r;
      scores[t] = sc * msk_cur;
    }
    __syncthreads();   // B2b: scores ready
    // ---- (h) out[b][e] = sum_l scores[l]*K[l][e]; stage next q row ----
    if (t < E_DIM) {
      float o = 0.f;
#pragma unroll
      for (int l = 0; l < L_SEQ; ++l)
        o += scores[l] * (float)Kb[l * KSTR + t];
      out[(size_t)(b0 + i) * E_DIM + t] = o;
    }
    if (i + 1 < NB && t < 32)
      *(float4*)&qrowf[(i + 1) & 1][qcol] = qbuf;
    msk_cur = msk_nx;
    __syncthreads();   // B3: Kb free, next qrowf visible
  }
#undef LOAD_IDS
#undef ISSUE_GATHER
}

extern "C" void kernel_launch(void* const* d_in, const int* in_sizes, int n_in,
                              void* d_out, int out_size, void* d_ws, size_t ws_size,
                              hipStream_t stream) {
  const int* qid_item = (const int*)d_in[0];
  const int* qid_cate = (const int*)d_in[1];
  const int* seq_item = (const int*)d_in[2];
  const int* seq_cate = (const int*)d_in[3];
  const int* mask     = (const int*)d_in[4];
  const float* emb_item = (const float*)d_in[5];
  const float* emb_cate = (const float*)d_in[6];
  const float* W_hide   = (const float*)d_in[7];
  const float* b_hide   = (const float*)d_in[8];
  const float* W_out    = (const float*)d_in[9];
  const float* b_out    = (const float*)d_in[10];
  float* out = (float*)d_out;

  (void)d_ws; (void)ws_size;

  pack_kernel<<<384, 256, 0, stream>>>(W_hide);
  din_main_kernel<<<4096 / NB, 256, 0, stream>>>(
      qid_item, qid_cate, seq_item, seq_cate, mask, emb_item, emb_cate,
      b_hide, W_out, b_out, out);
}

// Round 8
// 238.549 us; speedup vs baseline: 1.5316x; 1.5316x over previous
//
#include <hip/hip_runtime.h>
#include <hip/hip_bf16.h>

// B=4096, L=50, D=64, E=128, CAT=384, U=256, V=100000. fp32 I/O, int32 ids.
// h = relu([q | K | K*q]·[W_q;W_k;W_qk] + b_hide); scores=(h·W_out+b_out)*mask;
// out = scores·K.
//
// R8: 256 blocks × 1024 threads (16 waves), NB=16 batches/block.
// Each wave owns 16 N-cols -> ALL its weight fragments = 12×bf16x8 = 48 VGPRs,
// loaded once per block, reused for 16 batches (R7 reloaded 512 KB/block/batch
// from L2 and spilled: VGPR=128 vs ~200 demand -> 73 MB scratch writes).
// qvec folded into MFMA: q broadcast as A-fragment vs W_q section -> accq
// (rows identical; epilogue adds accq[rg]). Peak regs ~110 < 128 cap. Grid
// 256 = 1 block/CU; gathers for batch i+1 in flight through batch i's MFMA.

#define L_SEQ 50
#define D_EMB 64
#define E_DIM 128
#define U_DIM 256
#define V_SZ  100000
#define KSTR  136   // LDS row stride (bf16): rows 16B-aligned
#define NB    16    // batches per block; grid = 4096/NB = 256

typedef __bf16 bf16x4 __attribute__((ext_vector_type(4)));
typedef __bf16 bf16x8 __attribute__((ext_vector_type(8)));
typedef float  f32x4  __attribute__((ext_vector_type(4)));

// packed: g_Wp[kk8*2048 + n*8 + j] = bf16(W_hide[kk8*8+j][n]), kk8 in [0,48)
// kk8 0..15 -> W_q rows; 16..31 -> W_k rows; 32..47 -> W_qk rows
__device__ __bf16 g_Wp[48 * 256 * 8];

__global__ __launch_bounds__(256) void pack_kernel(const float* __restrict__ W) {
  int e = blockIdx.x * 256 + threadIdx.x;          // grid 384 -> exact cover
  int kk8 = e >> 11, rem = e & 2047, n = rem >> 3, j = rem & 7;
  g_Wp[e] = (__bf16)W[(kk8 * 8 + j) * 256 + n];
}

__global__ __launch_bounds__(1024) void din_main_kernel(
    const int* __restrict__ qid_item, const int* __restrict__ qid_cate,
    const int* __restrict__ seq_item, const int* __restrict__ seq_cate,
    const int* __restrict__ mask,
    const float* __restrict__ emb_item,
    const float* __restrict__ emb_cate,
    const float* __restrict__ b_hide,
    const float* __restrict__ W_out,
    const float* __restrict__ b_out,
    float* __restrict__ out) {
  __shared__ alignas(16) __bf16 Kb[2][64 * KSTR];  // 2 x 17408 B
  __shared__ alignas(16) float qrowf[2][E_DIM];
  __shared__ float scpart[16][64];
  __shared__ float scores[64];
  __shared__ float opart[4][E_DIM];

  const int t = threadIdx.x;
  const int b0 = blockIdx.x * NB;
  const int row = t >> 4, col4 = t & 15;           // gather: 64 rows x 16 thr
  const int rowc = (row < L_SEQ) ? row : (L_SEQ - 1);   // dup-load pad rows
  const int wave = t >> 6, lane = t & 63;
  const int m = lane & 15, quad = lane >> 4;
  const int n_lane = wave * 16 + m;                // this lane's N-column
  const float bh_r = b_hide[n_lane];
  const float wo_r = W_out[n_lane];
  const float bo_r = b_out[0];
  const float* qembsel = (t < 16) ? emb_item : emb_cate;
  const int qcol = (t < 16) ? t * 4 : 64 + (t - 16) * 4;

  // ---- persistent weight fragments: 12 x 16B = 48 VGPRs, loaded ONCE ----
  bf16x8 bqq[4], bk[4], bq[4];
#pragma unroll
  for (int s = 0; s < 4; ++s) {
    const int noff = n_lane * 8;
    bqq[s] = *(const bf16x8*)&g_Wp[((s * 4 + quad) << 11) + noff];
    bk[s]  = *(const bf16x8*)&g_Wp[((16 + s * 4 + quad) << 11) + noff];
    bq[s]  = *(const bf16x8*)&g_Wp[((32 + s * 4 + quad) << 11) + noff];
  }

#define LOAD_IDS(ii, si, ci, qi) {                                          \
    int bb_ = b0 + (((ii) < NB) ? (ii) : NB - 1);                           \
    si = seq_item[bb_ * L_SEQ + rowc];                                      \
    if ((unsigned)si >= (unsigned)V_SZ) si = 0;                             \
    ci = seq_cate[bb_ * L_SEQ + rowc];                                      \
    if ((unsigned)ci >= (unsigned)V_SZ) ci = 0;                             \
    qi = 0;                                                                 \
    if (t < 32) {                                                           \
      qi = (t < 16 ? qid_item : qid_cate)[bb_];                             \
      if ((unsigned)qi >= (unsigned)V_SZ) qi = 0;                           \
    } }

#define GATHER(si, ci, qi) {                                                \
    ki = *(const float4*)(emb_item + (size_t)(si) * D_EMB + col4 * 4);      \
    kc = *(const float4*)(emb_cate + (size_t)(ci) * D_EMB + col4 * 4);      \
    if (t < 32)                                                             \
      qb = *(const float4*)(qembsel + (size_t)(qi) * D_EMB + (t & 15) * 4); }

#define LOAD_MSK(ii, dst) {                                                 \
    int bb_ = b0 + (((ii) < NB) ? (ii) : NB - 1);                           \
    dst = (t < L_SEQ) ? ((mask[bb_ * L_SEQ + t] != 0) ? 1.f : 0.f) : 0.f; }

  // ---- prologue: prime the pipeline ----
  float4 ki, kc, qb;
  int si_n, ci_n, qi_n;
  float msk_cur, msk_nx;
  {
    int si, ci, qi;
    LOAD_IDS(0, si, ci, qi);
    GATHER(si, ci, qi);
  }
  LOAD_IDS(1, si_n, ci_n, qi_n);
  LOAD_MSK(0, msk_cur);
  if (t < 32) *(float4*)&qrowf[0][qcol] = qb;
  __syncthreads();

  for (int i = 0; i < NB; ++i) {
    const int cur = i & 1;

    // ---- (a) store gathered K row-slices to Kb[cur] (bf16) ----
    {
      bf16x4 s_i = {(__bf16)ki.x, (__bf16)ki.y, (__bf16)ki.z, (__bf16)ki.w};
      bf16x4 s_c = {(__bf16)kc.x, (__bf16)kc.y, (__bf16)kc.z, (__bf16)kc.w};
      *(bf16x4*)&Kb[cur][row * KSTR + col4 * 4] = s_i;
      *(bf16x4*)&Kb[cur][row * KSTR + 64 + col4 * 4] = s_c;
    }
    // ---- (b) prefetch batch i+1 (in flight through MFMA+epilogue) ----
    GATHER(si_n, ci_n, qi_n);          // ki/kc/qb now hold batch i+1
    LOAD_IDS(i + 2, si_n, ci_n, qi_n);
    LOAD_MSK(i + 1, msk_nx);
    __syncthreads();   // B1: Kb[cur] + qrowf[cur] visible

    // ---- (c) MFMA: M=64 (4 mt), N=16/wave, K=3x128 via 4 k-steps ----
    f32x4 acc[4], accq;
#pragma unroll
    for (int mt = 0; mt < 4; ++mt) acc[mt] = (f32x4){0.f, 0.f, 0.f, 0.f};
    accq = (f32x4){0.f, 0.f, 0.f, 0.f};
#pragma unroll
    for (int s = 0; s < 4; ++s) {
      const int klocal = s * 32 + quad * 8;
      const float4 qa  = *(const float4*)&qrowf[cur][klocal];
      const float4 qb4 = *(const float4*)&qrowf[cur][klocal + 4];
      bf16x8 aq;
      aq[0] = (__bf16)qa.x;  aq[1] = (__bf16)qa.y;
      aq[2] = (__bf16)qa.z;  aq[3] = (__bf16)qa.w;
      aq[4] = (__bf16)qb4.x; aq[5] = (__bf16)qb4.y;
      aq[6] = (__bf16)qb4.z; aq[7] = (__bf16)qb4.w;
      accq = __builtin_amdgcn_mfma_f32_16x16x32_bf16(aq, bqq[s], accq, 0, 0, 0);
#pragma unroll
      for (int mt = 0; mt < 4; ++mt) {
        bf16x8 af = *(const bf16x8*)&Kb[cur][(mt * 16 + m) * KSTR + klocal];
        acc[mt] = __builtin_amdgcn_mfma_f32_16x16x32_bf16(af, bk[s], acc[mt], 0, 0, 0);
        bf16x8 a2;
        a2[0] = (__bf16)((float)af[0] * qa.x);
        a2[1] = (__bf16)((float)af[1] * qa.y);
        a2[2] = (__bf16)((float)af[2] * qa.z);
        a2[3] = (__bf16)((float)af[3] * qa.w);
        a2[4] = (__bf16)((float)af[4] * qb4.x);
        a2[5] = (__bf16)((float)af[5] * qb4.y);
        a2[6] = (__bf16)((float)af[6] * qb4.z);
        a2[7] = (__bf16)((float)af[7] * qb4.w);
        acc[mt] = __builtin_amdgcn_mfma_f32_16x16x32_bf16(a2, bq[s], acc[mt], 0, 0, 0);
      }
    }

    // ---- (d) epilogue: h=relu(acc+accq+bh); per-lane score partials ----
    float part[16];
#pragma unroll
    for (int mt = 0; mt < 4; ++mt)
#pragma unroll
      for (int rg = 0; rg < 4; ++rg) {
        float h = acc[mt][rg] + accq[rg] + bh_r;
        part[mt * 4 + rg] = fmaxf(h, 0.f) * wo_r;
      }
#pragma unroll
    for (int off = 1; off < 16; off <<= 1)
#pragma unroll
      for (int k = 0; k < 16; ++k)
        part[k] += __shfl_xor(part[k], off, 64);
    if (m == 0) {
#pragma unroll
      for (int mt = 0; mt < 4; ++mt)
#pragma unroll
        for (int rg = 0; rg < 4; ++rg)
          scpart[wave][mt * 16 + quad * 4 + rg] = part[mt * 4 + rg];
    }
    __syncthreads();   // B2: scpart ready
    if (t < 64) {
      float sc = bo_r;
#pragma unroll
      for (int w = 0; w < 16; ++w) sc += scpart[w][t];
      scores[t] = sc * msk_cur;
    }
    __syncthreads();   // B3: scores ready

    // ---- (e) out partials: 512 threads, 4 L-segments ----
    if (t < 512) {
      const int e = t & 127, seg = t >> 7;
      const int l0 = seg * 13;
      const int l1 = (seg == 3) ? L_SEQ : l0 + 13;
      float sum = 0.f;
      for (int l = l0; l < l1; ++l)
        sum += scores[l] * (float)Kb[cur][l * KSTR + e];
      opart[seg][e] = sum;
    }
    if (t < 32) *(float4*)&qrowf[(i + 1) & 1][qcol] = qb;  // next batch's q
    msk_cur = msk_nx;
    __syncthreads();   // B4: opart + next qrowf visible
    if (t < E_DIM)
      out[(size_t)(b0 + i) * E_DIM + t] =
          opart[0][t] + opart[1][t] + opart[2][t] + opart[3][t];
  }
#undef LOAD_IDS
#undef GATHER
#undef LOAD_MSK
}

extern "C" void kernel_launch(void* const* d_in, const int* in_sizes, int n_in,
                              void* d_out, int out_size, void* d_ws, size_t ws_size,
                              hipStream_t stream) {
  const int* qid_item = (const int*)d_in[0];
  const int* qid_cate = (const int*)d_in[1];
  const int* seq_item = (const int*)d_in[2];
  const int* seq_cate = (const int*)d_in[3];
  const int* mask     = (const int*)d_in[4];
  const float* emb_item = (const float*)d_in[5];
  const float* emb_cate = (const float*)d_in[6];
  const float* W_hide   = (const float*)d_in[7];
  const float* b_hide   = (const float*)d_in[8];
  const float* W_out    = (const float*)d_in[9];
  const float* b_out    = (const float*)d_in[10];
  float* out = (float*)d_out;

  (void)d_ws; (void)ws_size;

  pack_kernel<<<384, 256, 0, stream>>>(W_hide);
  din_main_kernel<<<4096 / NB, 1024, 0, stream>>>(
      qid_item, qid_cate, seq_item, seq_cate, mask, emb_item, emb_cate,
      b_hide, W_out, b_out, out);
}

// Round 9
// 232.733 us; speedup vs baseline: 1.5699x; 1.0250x over previous
//
#include <hip/hip_runtime.h>
#include <hip/hip_bf16.h>

// B=4096, L=50, D=64, E=128, CAT=384, U=256, V=100000. fp32 I/O, int32 ids.
// h = relu(q·W_q + K·(W_k + diag(q)·W_qk) + b_hide)      [B'' fusion]
// scores = (h·W_out + b_out)*mask ; out = scores·K
//
// R9: 256 blocks x 1024 thr (16 waves), NB=16. ONE barrier per batch.
// Per wave: 16 U-cols; weights (12 bf16x8 = 48 VGPR) persistent.
// B'' = bk + q∘bq built in regs (q k-indices == B-fragment lane k) ->
// 20 MFMA/wave/batch (was 36) and no A2 construction (was 192 VALU).
// Tail (scores+out of batch i) on wave i only, overlapped with other
// waves' batch i+1 MFMA. Kb triple-buffered, qrowf/scpart double ->
// race-free with skew <= 1 iteration.

#define L_SEQ 50
#define D_EMB 64
#define E_DIM 128
#define V_SZ  100000
#define KSTR  136   // LDS row stride (bf16): rows 16B-aligned
#define NB    16    // batches per block == waves per block

typedef __bf16 bf16x2 __attribute__((ext_vector_type(2)));
typedef __bf16 bf16x4 __attribute__((ext_vector_type(4)));
typedef __bf16 bf16x8 __attribute__((ext_vector_type(8)));
typedef float  f32x4  __attribute__((ext_vector_type(4)));

// packed: g_Wp[kk8*2048 + n*8 + j] = bf16(W_hide[kk8*8+j][n]), kk8 in [0,48)
// kk8 0..15 -> W_q; 16..31 -> W_k; 32..47 -> W_qk
__device__ __bf16 g_Wp[48 * 256 * 8];

__global__ __launch_bounds__(256) void pack_kernel(const float* __restrict__ W) {
  int e = blockIdx.x * 256 + threadIdx.x;          // grid 384 -> exact cover
  int kk8 = e >> 11, rem = e & 2047, n = rem >> 3, j = rem & 7;
  g_Wp[e] = (__bf16)W[(kk8 * 8 + j) * 256 + n];
}

__global__ __launch_bounds__(1024) void din_main_kernel(
    const int* __restrict__ qid_item, const int* __restrict__ qid_cate,
    const int* __restrict__ seq_item, const int* __restrict__ seq_cate,
    const int* __restrict__ mask,
    const float* __restrict__ emb_item,
    const float* __restrict__ emb_cate,
    const float* __restrict__ b_hide,
    const float* __restrict__ W_out,
    const float* __restrict__ b_out,
    float* __restrict__ out) {
  __shared__ alignas(16) __bf16 Kb[3][64 * KSTR];  // 3 x 17408 B
  __shared__ alignas(16) float qrowf[2][E_DIM];
  __shared__ float scpart[2][16][64];

  const int t = threadIdx.x;
  const int b0 = blockIdx.x * NB;
  const int row = t >> 4, col4 = t & 15;            // gather: 64 rows x 16 thr
  const int rowc = (row < L_SEQ) ? row : (L_SEQ - 1);   // dup-load pad rows
  const int wave = t >> 6, lane = t & 63;
  const int m = lane & 15, quad = lane >> 4;
  const int n_lane = wave * 16 + m;                 // this lane's U-column

  const float bh_r = b_hide[n_lane];
  const float wo_r = W_out[n_lane];
  const float bo_r = b_out[0];
  // per-wave mask for its tail batch (b0+wave); 0 for lanes >= L_SEQ
  float msk = 0.f;
  if (lane < L_SEQ)
    msk = (mask[(b0 + wave) * L_SEQ + lane] != 0) ? 1.f : 0.f;

  // ---- persistent weight fragments: 12 x 16B = 48 VGPRs, loaded ONCE ----
  bf16x8 bqq[4], bk[4], bq[4];
#pragma unroll
  for (int s = 0; s < 4; ++s) {
    const int noff = n_lane * 8;
    bqq[s] = *(const bf16x8*)&g_Wp[((s * 4 + quad) << 11) + noff];
    bk[s]  = *(const bf16x8*)&g_Wp[((16 + s * 4 + quad) << 11) + noff];
    bq[s]  = *(const bf16x8*)&g_Wp[((32 + s * 4 + quad) << 11) + noff];
  }

  const float* qembsel = (t < 16) ? emb_item : emb_cate;
  const int qcol = (t < 16) ? t * 4 : 64 + (t - 16) * 4;

#define LOAD_IDS(ii, si, ci, qi) {                                          \
    int bb_ = b0 + (((ii) < NB) ? (ii) : NB - 1);                           \
    si = seq_item[bb_ * L_SEQ + rowc];                                      \
    if ((unsigned)si >= (unsigned)V_SZ) si = 0;                             \
    ci = seq_cate[bb_ * L_SEQ + rowc];                                      \
    if ((unsigned)ci >= (unsigned)V_SZ) ci = 0;                             \
    qi = 0;                                                                 \
    if (t < 32) {                                                           \
      qi = (t < 16 ? qid_item : qid_cate)[bb_];                             \
      if ((unsigned)qi >= (unsigned)V_SZ) qi = 0;                           \
    } }

#define GATHER(si, ci, qi) {                                                \
    ki = *(const float4*)(emb_item + (size_t)(si) * D_EMB + col4 * 4);      \
    kc = *(const float4*)(emb_cate + (size_t)(ci) * D_EMB + col4 * 4);      \
    if (t < 32)                                                             \
      qb = *(const float4*)(qembsel + (size_t)(qi) * D_EMB + (t & 15) * 4); }

  // ---- prologue: prime batch 0 into Kb[0]/qrowf[0]; batch 1 in regs ----
  float4 ki, kc, qb;
  int si_n, ci_n, qi_n;
  {
    int si, ci, qi;
    LOAD_IDS(0, si, ci, qi);
    GATHER(si, ci, qi);
  }
  {
    bf16x4 hi = {(__bf16)ki.x, (__bf16)ki.y, (__bf16)ki.z, (__bf16)ki.w};
    bf16x4 hc = {(__bf16)kc.x, (__bf16)kc.y, (__bf16)kc.z, (__bf16)kc.w};
    *(bf16x4*)&Kb[0][row * KSTR + col4 * 4] = hi;
    *(bf16x4*)&Kb[0][row * KSTR + 64 + col4 * 4] = hc;
    if (t < 32) *(float4*)&qrowf[0][qcol] = qb;
  }
  LOAD_IDS(1, si_n, ci_n, qi_n);
  GATHER(si_n, ci_n, qi_n);          // batch 1 -> regs
  LOAD_IDS(2, si_n, ci_n, qi_n);     // ids for batch 2
  __syncthreads();                   // Kb[0], qrowf[0] visible

  int cur = 0;
  for (int i = 0; i < NB; ++i) {
    const int nxt = (cur == 2) ? 0 : cur + 1;
    const int sp = i & 1, spx = sp ^ 1;

    // ---- (1) store prefetched batch i+1 -> Kb[nxt], qrowf[spx] ----
    if (i + 1 < NB) {
      bf16x4 hi = {(__bf16)ki.x, (__bf16)ki.y, (__bf16)ki.z, (__bf16)ki.w};
      bf16x4 hc = {(__bf16)kc.x, (__bf16)kc.y, (__bf16)kc.z, (__bf16)kc.w};
      *(bf16x4*)&Kb[nxt][row * KSTR + col4 * 4] = hi;
      *(bf16x4*)&Kb[nxt][row * KSTR + 64 + col4 * 4] = hc;
      if (t < 32) *(float4*)&qrowf[spx][qcol] = qb;
    }

    // ---- (2) MFMA batch i: 4 k-steps x (1 accq + 4 mt) = 20 MFMA ----
    f32x4 acc[4], accq;
#pragma unroll
    for (int mt = 0; mt < 4; ++mt) acc[mt] = (f32x4){0.f, 0.f, 0.f, 0.f};
    accq = (f32x4){0.f, 0.f, 0.f, 0.f};
#pragma unroll
    for (int s = 0; s < 4; ++s) {
      const int klocal = s * 32 + quad * 8;
      const float4 qa = *(const float4*)&qrowf[sp][klocal];
      const float4 q2 = *(const float4*)&qrowf[sp][klocal + 4];
      const float qv[8] = {qa.x, qa.y, qa.z, qa.w, q2.x, q2.y, q2.z, q2.w};
      bf16x8 aq, bs;
#pragma unroll
      for (int j = 0; j < 8; ++j) {
        aq[j] = (__bf16)qv[j];
        bs[j] = (__bf16)((float)bk[s][j] + qv[j] * (float)bq[s][j]);  // B''
      }
      accq = __builtin_amdgcn_mfma_f32_16x16x32_bf16(aq, bqq[s], accq, 0, 0, 0);
#pragma unroll
      for (int mt = 0; mt < 4; ++mt) {
        bf16x8 af = *(const bf16x8*)&Kb[cur][(mt * 16 + m) * KSTR + klocal];
        acc[mt] = __builtin_amdgcn_mfma_f32_16x16x32_bf16(af, bs, acc[mt], 0, 0, 0);
      }
    }

    // ---- (3) issue gathers for batch i+2 (fly through epilogue+barrier) ----
    if (i + 2 < NB) { GATHER(si_n, ci_n, qi_n); }
    LOAD_IDS(i + 3, si_n, ci_n, qi_n);

    // ---- (4) epilogue: part = relu(acc+qvec+bh)*wo; 16-lane butterfly ----
    const float qadd = accq[0] + bh_r;   // accq rows identical by construction
    float part[16];
#pragma unroll
    for (int mt = 0; mt < 4; ++mt)
#pragma unroll
      for (int rg = 0; rg < 4; ++rg)
        part[mt * 4 + rg] = fmaxf(acc[mt][rg] + qadd, 0.f) * wo_r;
#pragma unroll
    for (int off = 1; off < 16; off <<= 1)
#pragma unroll
      for (int k = 0; k < 16; ++k)
        part[k] += __shfl_xor(part[k], off, 64);
    if (m == 0) {
#pragma unroll
      for (int mt = 0; mt < 4; ++mt) {
        f32x4 v = {part[mt * 4 + 0], part[mt * 4 + 1],
                   part[mt * 4 + 2], part[mt * 4 + 3]};
        *(f32x4*)&scpart[sp][wave][mt * 16 + quad * 4] = v;
      }
    }
    __syncthreads();   // THE barrier: scpart[sp], Kb[nxt], qrowf[spx] visible

    // ---- (5) tail for batch i on wave i only (others run ahead) ----
    if (wave == i) {
      float sc = bo_r;
#pragma unroll
      for (int w = 0; w < 16; ++w) sc += scpart[sp][w][lane];
      sc *= msk;                                   // 0 for lane >= 50
      float o0 = 0.f, o1 = 0.f;
      const __bf16* kbc = &Kb[cur][lane * 2];
#pragma unroll
      for (int l = 0; l < L_SEQ; ++l) {
        float sb = __shfl(sc, l, 64);
        bf16x2 kv = *(const bf16x2*)&kbc[l * KSTR];
        o0 += sb * (float)kv[0];
        o1 += sb * (float)kv[1];
      }
      *(float2*)&out[(size_t)(b0 + i) * E_DIM + lane * 2] = make_float2(o0, o1);
    }
    cur = nxt;
  }
#undef LOAD_IDS
#undef GATHER
}

extern "C" void kernel_launch(void* const* d_in, const int* in_sizes, int n_in,
                              void* d_out, int out_size, void* d_ws, size_t ws_size,
                              hipStream_t stream) {
  const int* qid_item = (const int*)d_in[0];
  const int* qid_cate = (const int*)d_in[1];
  const int* seq_item = (const int*)d_in[2];
  const int* seq_cate = (const int*)d_in[3];
  const int* mask     = (const int*)d_in[4];
  const float* emb_item = (const float*)d_in[5];
  const float* emb_cate = (const float*)d_in[6];
  const float* W_hide   = (const float*)d_in[7];
  const float* b_hide   = (const float*)d_in[8];
  const float* W_out    = (const float*)d_in[9];
  const float* b_out    = (const float*)d_in[10];
  float* out = (float*)d_out;

  (void)d_ws; (void)ws_size;

  pack_kernel<<<384, 256, 0, stream>>>(W_hide);
  din_main_kernel<<<4096 / NB, 1024, 0, stream>>>(
      qid_item, qid_cate, seq_item, seq_cate, mask, emb_item, emb_cate,
      b_hide, W_out, b_out, out);
}